// Round 14
// baseline (3968.482 us; speedup 1.0000x reference)
//
#include <hip/hip_runtime.h>
#include <hip/hip_bf16.h>
#include <math.h>

#define T_TOK 4096
#define HID   2560
#define NEXP  32
#define KTOP  6
#define FF    1536
#define SFF   3072
#define MAXP  (T_TOK*KTOP)

typedef __attribute__((ext_vector_type(8))) short short8;
typedef __attribute__((ext_vector_type(4))) float f32x4;

static __device__ __forceinline__ unsigned short f2bf(float x){
  return __builtin_bit_cast(unsigned short, (__bf16)x);
}
static __device__ __forceinline__ float bf2f(unsigned short u){
  unsigned int x = ((unsigned int)u) << 16;
  return __builtin_bit_cast(float, x);
}
static __device__ __forceinline__ unsigned int pk2bf(float a, float b){
  return (unsigned int)f2bf(a) | ((unsigned int)f2bf(b) << 16);
}

static __device__ __forceinline__ void gload_lds16(const void* g, void* l){
  __builtin_amdgcn_global_load_lds(
      (const __attribute__((address_space(1))) unsigned int*)g,
      (__attribute__((address_space(3))) unsigned int*)l, 16, 0, 0);
}

// ---------------- cast hidden fp32 -> bf16 ----------------
__global__ void k_cast_x(const float* __restrict__ x, unsigned short* __restrict__ xb){
  int i = (blockIdx.x * 256 + threadIdx.x) * 4;
  float4 v = *(const float4*)(x + i);
  ushort4 o;
  o.x = f2bf(v.x); o.y = f2bf(v.y); o.z = f2bf(v.z); o.w = f2bf(v.w);
  *(ushort4*)(xb + i) = o;
}

// ---------------- router ----------------
__global__ void k_router(const float* __restrict__ x, const float* __restrict__ rw,
                         const float* __restrict__ rb, float* __restrict__ top_w,
                         int* __restrict__ top_i, int* __restrict__ counts){
  const int lane = threadIdx.x & 63;
  const int wv   = threadIdx.x >> 6;
  const int t    = blockIdx.x * 4 + wv;
  const float* xr = x + (size_t)t * HID;
  float xv[40];
#pragma unroll
  for (int i = 0; i < 40; ++i) xv[i] = xr[lane + 64*i];
  float sc[32];
  for (int e = 0; e < 32; ++e){
    const float* w = rw + (size_t)e * HID;
    float s = 0.f;
#pragma unroll
    for (int i = 0; i < 40; ++i) s = fmaf(xv[i], w[lane + 64*i], s);
#pragma unroll
    for (int o = 32; o; o >>= 1) s += __shfl_xor(s, o);
    sc[e] = s;
  }
  float mx = sc[0];
#pragma unroll
  for (int e = 1; e < 32; ++e) mx = fmaxf(mx, sc[e]);
  float se = 0.f;
#pragma unroll
  for (int e = 0; e < 32; ++e){ sc[e] = expf(sc[e] - mx); se += sc[e]; }
  const float inv = 1.f / se;
#pragma unroll
  for (int e = 0; e < 32; ++e) sc[e] = sc[e] * inv + rb[e];

  unsigned chosen = 0; float swv[KTOP]; int sid[KTOP]; float wsum = 0.f;
#pragma unroll
  for (int k = 0; k < KTOP; ++k){
    float bv = -1e30f; int bi = 0;
#pragma unroll
    for (int e = 0; e < 32; ++e){
      bool ok = !((chosen >> e) & 1u);
      if (ok && sc[e] > bv){ bv = sc[e]; bi = e; }
    }
    chosen |= 1u << bi; swv[k] = bv; sid[k] = bi; wsum += bv;
  }
  const float dn = fmaxf(wsum, 1e-12f);
  if (lane < KTOP){
    top_w[t*KTOP + lane] = swv[lane] / dn;
    top_i[t*KTOP + lane] = sid[lane];
    atomicAdd(counts + sid[lane], 1);
  }
}

__global__ void k_scan(const int* __restrict__ counts, int* __restrict__ offsets){
  if (threadIdx.x == 0){
    int a = 0;
    for (int e = 0; e < NEXP; ++e){ offsets[e] = a; a += counts[e]; }
    offsets[NEXP] = a;
  }
}

__global__ void k_scatter(const int* __restrict__ top_i, const float* __restrict__ top_w,
                          const int* __restrict__ offsets, int* __restrict__ cursor,
                          int* __restrict__ pair_tok, float* __restrict__ pair_w){
  const int t = blockIdx.x * 256 + threadIdx.x;
  if (t >= T_TOK) return;
#pragma unroll
  for (int k = 0; k < KTOP; ++k){
    int e = top_i[t*KTOP + k];
    int pos = offsets[e] + atomicAdd(cursor + e, 1);
    pair_tok[pos] = t;
    pair_w[pos]   = top_w[t*KTOP + k];
  }
}

// ---------------- SwiGLU: act[p][F] = silu(y[p][f]) * y[p][F+f] ----------------
template<int F8>
__global__ __launch_bounds__(256)
void k_swiglu(const unsigned short* __restrict__ y, unsigned short* __restrict__ act){
  const int i = blockIdx.x * 256 + threadIdx.x;
  const int p = i / F8, c = i % F8;
  const unsigned short* row = y + (size_t)p * (2*F8*8);
  short8 g8 = *(const short8*)(row + c*8);
  short8 u8 = *(const short8*)(row + F8*8 + c*8);
  short8 o;
#pragma unroll
  for (int j = 0; j < 8; ++j){
    float g = bf2f((unsigned short)g8[j]);
    float u = bf2f((unsigned short)u8[j]);
    float s = (g / (1.f + expf(-g))) * u;
    o[j] = (short)f2bf(s);
  }
  *(short8*)(act + (size_t)p*F8*8 + c*8) = o;
}

// ---------------- grouped GEMM, 256x256 tile, 8 waves, 4-slot ring, fp32-direct B ----------------
// A: bf16 [rows][K] via global_load_lds. B: fp32 k-major [K][strideB] -> regs -> cvt -> swizzled
// [n][k] LDS (no transpose prepass). Deterministic retire: end-of-phase counted vmcnt sized to
// THIS phase's issues, so all prior-phase VMEM is retired regardless of intra-phase issue order.
template<bool GROUPED, bool GATHER, int OUT, bool HASB2>
__global__ __launch_bounds__(512, 1)
void k_gemm(const unsigned short* __restrict__ A,
            const float* __restrict__ Bg, const float* __restrict__ Bu,
            void* __restrict__ outp,
            const int* __restrict__ pair_tok, const float* __restrict__ pair_w,
            const int* __restrict__ counts, const int* __restrict__ offsets,
            const int N, const int K, const int strideB, const int ntiles)
{
  const int NH = K >> 5;                 // K-halves of 32
  const int total = gridDim.x;
  const int phys  = blockIdx.x;
  const int logical = (phys & 7) * (total >> 3) + (phys >> 3);
  const int mt   = logical & 15;         // 16 m-tiles of 256
  const int rest = logical >> 4;
  const int nt   = rest % ntiles;
  const int e    = rest / ntiles;
  const int n0   = nt << 8;              // col in N' space (output)

  int M, base;
  if (GROUPED){ M = counts[e]; base = offsets[e]; }
  else        { M = T_TOK;     base = 0; }
  if (mt * 256 >= M) return;

  // B source select (gate|up split at ntiles/2 when HASB2)
  const float* bsrcbase;
  int ncol0;
  if (HASB2){
    const int split = ntiles >> 1;
    if (nt < split){ bsrcbase = Bg; ncol0 = nt << 8; }
    else           { bsrcbase = Bu; ncol0 = (nt - split) << 8; }
  } else { bsrcbase = Bg; ncol0 = nt << 8; }
  if (GROUPED) bsrcbase += (size_t)e * (size_t)K * strideB;

  __shared__ unsigned short AS[4*8192];  // 4 slots x 256 rows x 32k bf16 (64 KB)
  __shared__ unsigned short BS[4*8192];  // 64 KB

  const int tid  = threadIdx.x;
  const int lane = tid & 63;
  const int w    = tid >> 6;             // 0..7
  const int wr = w >> 2, wc = w & 3;     // 2x4 wave grid, wave out = 128x64

  // ---- A staging: wave w covers rows w*32..+31, 2 gload_lds per slot ----
  const int lrow = lane >> 2, lchunk = lane & 3;
  const unsigned short *ap0, *ap1;
  {
    const int r0 = w*32 + lrow, r1 = w*32 + 16 + lrow;
    const int swz = (lchunk ^ ((r0 >> 1) & 3)) * 8;   // same key for r1 (r1=r0+16)
    int i0 = min(mt*256 + r0, M - 1);
    int i1 = min(mt*256 + r1, M - 1);
    int rowA0 = GATHER ? pair_tok[base + i0] : (GROUPED ? base + i0 : i0);
    int rowA1 = GATHER ? pair_tok[base + i1] : (GROUPED ? base + i1 : i1);
    ap0 = A + (size_t)rowA0 * K + swz;
    ap1 = A + (size_t)rowA1 * K + swz;
  }

  // ---- B reg-staging geometry: wave w -> kg = w&3 (8 k-rows), nh = w>>2 (128 n) ----
  const int kg = w & 3;
  const int nh = w >> 2;
  const int nn0 = nh*128 + 2*lane;       // tile-local row pair {nn0, nn0+1}; nn0 even
  const float* bsrc = bsrcbase + (size_t)(kg*8) * strideB + ncol0 + nn0;
  const int wslot = (kg ^ ((nn0 >> 1) & 3)) * 16;   // same key for nn0+1 (nn0 even)
  const int wbyte0 = nn0*64 + wslot;

  const f32x4 zero = {0.f,0.f,0.f,0.f};
  f32x4 acc[8][4];
#pragma unroll
  for (int m = 0; m < 8; ++m)
#pragma unroll
    for (int n = 0; n < 4; ++n) acc[m][n] = zero;

  const int fr = lane & 15;
  const int fg = ((lane >> 4) ^ ((lane >> 1) & 3)) * 16;

  float2 breg[2][8];

#define LOADB(buf, h)                                                       \
  { const float* _b = bsrc + (size_t)(h) * 32 * strideB;                    \
    _Pragma("unroll")                                                       \
    for (int j = 0; j < 8; ++j) breg[buf][j] = *(const float2*)(_b + (size_t)j * strideB); }

#define CVTWRITE(buf, sl)                                                   \
  { uint4 u0, u1;                                                           \
    u0.x = pk2bf(breg[buf][0].x, breg[buf][1].x);                           \
    u0.y = pk2bf(breg[buf][2].x, breg[buf][3].x);                           \
    u0.z = pk2bf(breg[buf][4].x, breg[buf][5].x);                           \
    u0.w = pk2bf(breg[buf][6].x, breg[buf][7].x);                           \
    u1.x = pk2bf(breg[buf][0].y, breg[buf][1].y);                           \
    u1.y = pk2bf(breg[buf][2].y, breg[buf][3].y);                           \
    u1.z = pk2bf(breg[buf][4].y, breg[buf][5].y);                           \
    u1.w = pk2bf(breg[buf][6].y, breg[buf][7].y);                           \
    *(uint4*)((char*)BS + (sl)*16384 + wbyte0)      = u0;                   \
    *(uint4*)((char*)BS + (sl)*16384 + wbyte0 + 64) = u1; }

#define STAGEA(h)                                                           \
  { const int _s = (h) & 3; const size_t _k = (size_t)(h) * 32;             \
    gload_lds16(ap0 + _k, (char*)AS + _s*16384 + (w*32)*64);                \
    gload_lds16(ap1 + _k, (char*)AS + _s*16384 + (w*32+16)*64); }

  // ---- prologue: full deterministic drain before first barrier ----
  LOADB(0, 0)
  STAGEA(0) STAGEA(1) STAGEA(2)
  CVTWRITE(0, 0)
  LOADB(1, 1)
  asm volatile("s_waitcnt vmcnt(0) lgkmcnt(0)" ::: "memory");
  __builtin_amdgcn_s_barrier();

#pragma unroll 4
  for (int h = 0; h < NH; ++h){
    const int s = h & 3;
    const char* _as = (const char*)AS + s*16384;
    const char* _bs = (const char*)BS + s*16384;
    short8 bq[4], af[8];
#pragma unroll
    for (int n = 0; n < 4; ++n)
      bq[n] = *(const short8*)(_bs + (wc*64 + n*16 + fr)*64 + fg);
#pragma unroll
    for (int m = 0; m < 8; ++m)
      af[m] = *(const short8*)(_as + (wr*128 + m*16 + fr)*64 + fg);
    if (h + 2 < NH) LOADB(h & 1, h + 2)
    if (h + 3 < NH) STAGEA(h + 3)
    if (h + 1 < NH) CVTWRITE((h + 1) & 1, (h + 1) & 3)
    __builtin_amdgcn_s_setprio(1);
#pragma unroll
    for (int m = 0; m < 8; ++m)
#pragma unroll
      for (int n = 0; n < 4; ++n)
        acc[m][n] = __builtin_amdgcn_mfma_f32_16x16x32_bf16(af[m], bq[n], acc[m][n], 0, 0, 0);
    __builtin_amdgcn_s_setprio(0);
    if (h + 1 < NH){
      // retire ALL prior-phase VMEM: allow only this phase's own issues to stay in flight
      if (h + 3 < NH)      asm volatile("s_waitcnt vmcnt(10) lgkmcnt(0)" ::: "memory");
      else if (h + 2 < NH) asm volatile("s_waitcnt vmcnt(8) lgkmcnt(0)" ::: "memory");
      else                 asm volatile("s_waitcnt vmcnt(0) lgkmcnt(0)" ::: "memory");
      __builtin_amdgcn_s_barrier();
    }
  }
#undef LOADB
#undef CVTWRITE
#undef STAGEA

#pragma unroll
  for (int m = 0; m < 8; ++m)
#pragma unroll
    for (int j = 0; j < 4; ++j){
      const int rr = mt*256 + wr*128 + m*16 + (lane >> 4)*4 + j;
      if (rr < M){
        const int col = n0 + wc*64 + fr;
        if (OUT == 0){
          unsigned short* orow = (unsigned short*)outp + (size_t)(base + rr) * N + col;
#pragma unroll
          for (int n = 0; n < 4; ++n) orow[n*16] = f2bf(acc[m][n][j]);
        } else if (OUT == 1){
          const int p = base + rr;
          const int tok = pair_tok[p];
          const float pw = pair_w[p];
          float* orow = (float*)outp + (size_t)tok * HID + col;
#pragma unroll
          for (int n = 0; n < 4; ++n) atomicAdd(orow + n*16, acc[m][n][j] * pw);
        } else {
          float* orow = (float*)outp + (size_t)rr * N + col;
#pragma unroll
          for (int n = 0; n < 4; ++n) orow[n*16] = acc[m][n][j];
        }
      }
    }
}

extern "C" void kernel_launch(void* const* d_in, const int* in_sizes, int n_in,
                              void* d_out, int out_size, void* d_ws, size_t ws_size,
                              hipStream_t stream)
{
  (void)in_sizes; (void)n_in; (void)out_size; (void)ws_size;
  const float* hid = (const float*)d_in[0];
  const float* rw  = (const float*)d_in[1];
  const float* rb  = (const float*)d_in[2];
  const float* gw  = (const float*)d_in[3];
  const float* uw  = (const float*)d_in[4];
  const float* dw  = (const float*)d_in[5];
  const float* sgw = (const float*)d_in[6];
  const float* suw = (const float*)d_in[7];
  const float* sdw = (const float*)d_in[8];
  float* out = (float*)d_out;

  char* ws = (char*)d_ws;
  size_t o = 0;
  unsigned short* xb   = (unsigned short*)(ws + o); o += (size_t)T_TOK*HID*2;       // 21 MB
  unsigned short* act  = (unsigned short*)(ws + o); o += (size_t)MAXP*FF*2;         // 75.5 MB
  unsigned short* sact = (unsigned short*)(ws + o); o += (size_t)T_TOK*SFF*2;       // 25 MB
  unsigned short* y    = (unsigned short*)(ws + o); o += (size_t)MAXP*2*FF*2;       // 151 MB
  unsigned short* sy   = (unsigned short*)(ws + o); o += (size_t)T_TOK*2*SFF*2;     // 50 MB
  float* top_w    = (float*)(ws + o); o += (size_t)T_TOK*KTOP*4;
  int*   top_i    = (int*)(ws + o);   o += (size_t)T_TOK*KTOP*4;
  float* pair_w   = (float*)(ws + o); o += (size_t)MAXP*4;
  int*   pair_tok = (int*)(ws + o);   o += (size_t)MAXP*4;
  int*   counts   = (int*)(ws + o);   o += NEXP*4;
  int*   offsets  = (int*)(ws + o);   o += (NEXP+1)*4;
  int*   cursor   = (int*)(ws + o);   o += NEXP*4;

  hipMemsetAsync(counts, 0, (NEXP + (NEXP+1) + NEXP) * sizeof(int), stream);

  k_cast_x<<<(T_TOK*HID)/1024, 256, 0, stream>>>(hid, xb);
  k_router<<<T_TOK/4, 256, 0, stream>>>(hid, rw, rb, top_w, top_i, counts);
  k_scan<<<1, 64, 0, stream>>>(counts, offsets);
  k_scatter<<<T_TOK/256, 256, 0, stream>>>(top_i, top_w, offsets, cursor, pair_tok, pair_w);

  // gate+up GEMMs directly from fp32 weights (N' = 2F, gate|up split), then SwiGLU
  k_gemm<true,  true,  0, true><<<16*(2*FF/256)*NEXP, 512, 0, stream>>>(
      xb, gw, uw, y, pair_tok, nullptr, counts, offsets, 2*FF, HID, FF, 2*FF/256);
  k_gemm<false, false, 0, true><<<16*(2*SFF/256), 512, 0, stream>>>(
      xb, sgw, suw, sy, nullptr, nullptr, nullptr, nullptr, 2*SFF, HID, SFF, 2*SFF/256);
  k_swiglu<FF/8><<<(MAXP*(FF/8))/256, 256, 0, stream>>>(y, act);
  k_swiglu<SFF/8><<<(T_TOK*(SFF/8))/256, 256, 0, stream>>>(sy, sact);

  // down GEMMs directly from fp32 weights: shared stores (init), expert atomically accumulates
  k_gemm<false, false, 2, false><<<16*(HID/256), 512, 0, stream>>>(
      sact, sdw, nullptr, out, nullptr, nullptr, nullptr, nullptr, HID, SFF, HID, HID/256);
  k_gemm<true,  false, 1, false><<<16*(HID/256)*NEXP, 512, 0, stream>>>(
      act, dw, nullptr, out, pair_tok, pair_w, counts, offsets, HID, FF, HID, HID/256);
}

// Round 15
// 1821.769 us; speedup vs baseline: 2.1784x; 2.1784x over previous
//
#include <hip/hip_runtime.h>
#include <hip/hip_bf16.h>
#include <math.h>

#define T_TOK 4096
#define HID   2560
#define NEXP  32
#define KTOP  6
#define FF    1536
#define SFF   3072
#define MAXP  (T_TOK*KTOP)

typedef __attribute__((ext_vector_type(8))) short short8;
typedef __attribute__((ext_vector_type(4))) float f32x4;

static __device__ __forceinline__ unsigned short f2bf(float x){
  return __builtin_bit_cast(unsigned short, (__bf16)x);
}
static __device__ __forceinline__ float bf2f(unsigned short u){
  unsigned int x = ((unsigned int)u) << 16;
  return __builtin_bit_cast(float, x);
}
static __device__ __forceinline__ unsigned int pk2bf(float a, float b){
  return (unsigned int)f2bf(a) | ((unsigned int)f2bf(b) << 16);
}

static __device__ __forceinline__ void gload_lds16(const void* g, void* l){
  __builtin_amdgcn_global_load_lds(
      (const __attribute__((address_space(1))) unsigned int*)g,
      (__attribute__((address_space(3))) unsigned int*)l, 16, 0, 0);
}

// ---------------- cast hidden fp32 -> bf16 ----------------
__global__ void k_cast_x(const float* __restrict__ x, unsigned short* __restrict__ xb){
  int i = (blockIdx.x * 256 + threadIdx.x) * 4;
  float4 v = *(const float4*)(x + i);
  ushort4 o;
  o.x = f2bf(v.x); o.y = f2bf(v.y); o.z = f2bf(v.z); o.w = f2bf(v.w);
  *(ushort4*)(xb + i) = o;
}

// ---------------- router ----------------
__global__ void k_router(const float* __restrict__ x, const float* __restrict__ rw,
                         const float* __restrict__ rb, float* __restrict__ top_w,
                         int* __restrict__ top_i, int* __restrict__ counts){
  const int lane = threadIdx.x & 63;
  const int wv   = threadIdx.x >> 6;
  const int t    = blockIdx.x * 4 + wv;
  const float* xr = x + (size_t)t * HID;
  float xv[40];
#pragma unroll
  for (int i = 0; i < 40; ++i) xv[i] = xr[lane + 64*i];
  float sc[32];
  for (int e = 0; e < 32; ++e){
    const float* w = rw + (size_t)e * HID;
    float s = 0.f;
#pragma unroll
    for (int i = 0; i < 40; ++i) s = fmaf(xv[i], w[lane + 64*i], s);
#pragma unroll
    for (int o = 32; o; o >>= 1) s += __shfl_xor(s, o);
    sc[e] = s;
  }
  float mx = sc[0];
#pragma unroll
  for (int e = 1; e < 32; ++e) mx = fmaxf(mx, sc[e]);
  float se = 0.f;
#pragma unroll
  for (int e = 0; e < 32; ++e){ sc[e] = expf(sc[e] - mx); se += sc[e]; }
  const float inv = 1.f / se;
#pragma unroll
  for (int e = 0; e < 32; ++e) sc[e] = sc[e] * inv + rb[e];

  unsigned chosen = 0; float swv[KTOP]; int sid[KTOP]; float wsum = 0.f;
#pragma unroll
  for (int k = 0; k < KTOP; ++k){
    float bv = -1e30f; int bi = 0;
#pragma unroll
    for (int e = 0; e < 32; ++e){
      bool ok = !((chosen >> e) & 1u);
      if (ok && sc[e] > bv){ bv = sc[e]; bi = e; }
    }
    chosen |= 1u << bi; swv[k] = bv; sid[k] = bi; wsum += bv;
  }
  const float dn = fmaxf(wsum, 1e-12f);
  if (lane < KTOP){
    top_w[t*KTOP + lane] = swv[lane] / dn;
    top_i[t*KTOP + lane] = sid[lane];
    atomicAdd(counts + sid[lane], 1);
  }
}

__global__ void k_scan(const int* __restrict__ counts, int* __restrict__ offsets){
  if (threadIdx.x == 0){
    int a = 0;
    for (int e = 0; e < NEXP; ++e){ offsets[e] = a; a += counts[e]; }
    offsets[NEXP] = a;
  }
}

__global__ void k_scatter(const int* __restrict__ top_i, const float* __restrict__ top_w,
                          const int* __restrict__ offsets, int* __restrict__ cursor,
                          int* __restrict__ pair_tok, float* __restrict__ pair_w){
  const int t = blockIdx.x * 256 + threadIdx.x;
  if (t >= T_TOK) return;
#pragma unroll
  for (int k = 0; k < KTOP; ++k){
    int e = top_i[t*KTOP + k];
    int pos = offsets[e] + atomicAdd(cursor + e, 1);
    pair_tok[pos] = t;
    pair_w[pos]   = top_w[t*KTOP + k];
  }
}

// ---------------- SwiGLU: act[p][F] = silu(y[p][f]) * y[p][F+f] ----------------
template<int F8>
__global__ __launch_bounds__(256)
void k_swiglu(const unsigned short* __restrict__ y, unsigned short* __restrict__ act){
  const int i = blockIdx.x * 256 + threadIdx.x;
  const int p = i / F8, c = i % F8;
  const unsigned short* row = y + (size_t)p * (2*F8*8);
  short8 g8 = *(const short8*)(row + c*8);
  short8 u8 = *(const short8*)(row + F8*8 + c*8);
  short8 o;
#pragma unroll
  for (int j = 0; j < 8; ++j){
    float g = bf2f((unsigned short)g8[j]);
    float u = bf2f((unsigned short)u8[j]);
    float s = (g / (1.f + expf(-g))) * u;
    o[j] = (short)f2bf(s);
  }
  *(short8*)(act + (size_t)p*F8*8 + c*8) = o;
}

// ---------------- grouped GEMM, 256x256 tile, 8 waves, 4-slot ring, fp32-direct B ----------------
// A: bf16 [rows][K] via global_load_lds. B: fp32 k-major [KV][SB] -> regs (static sets E/O) ->
// cvt -> swizzled [n][k] LDS. Lane l writes rows {l, l+64}: conflict-free 16B ds_writes.
// Deterministic end-of-phase counted vmcnt sized to this phase's issues.
template<bool GROUPED, bool GATHER, int OUT, bool HASB2, int KV, int SB>
__global__ __launch_bounds__(512, 1)
void k_gemm(const unsigned short* __restrict__ A,
            const float* __restrict__ Bg, const float* __restrict__ Bu,
            void* __restrict__ outp,
            const int* __restrict__ pair_tok, const float* __restrict__ pair_w,
            const int* __restrict__ counts, const int* __restrict__ offsets,
            const int N, const int ntiles)
{
  constexpr int NH = KV >> 5;            // K-halves of 32 (even for all instantiations)
  const int total = gridDim.x;
  const int phys  = blockIdx.x;
  const int logical = (phys & 7) * (total >> 3) + (phys >> 3);
  const int mt   = logical & 15;         // 16 m-tiles of 256
  const int rest = logical >> 4;
  const int nt   = rest % ntiles;
  const int e    = rest / ntiles;
  const int n0   = nt << 8;              // col in N' space (output)

  int M, base;
  if (GROUPED){ M = counts[e]; base = offsets[e]; }
  else        { M = T_TOK;     base = 0; }
  if (mt * 256 >= M) return;

  // B source select (gate|up split at ntiles/2 when HASB2)
  const float* bsrcbase;
  int ncol0;
  if (HASB2){
    const int split = ntiles >> 1;
    if (nt < split){ bsrcbase = Bg; ncol0 = nt << 8; }
    else           { bsrcbase = Bu; ncol0 = (nt - split) << 8; }
  } else { bsrcbase = Bg; ncol0 = nt << 8; }
  if (GROUPED) bsrcbase += (size_t)e * (size_t)KV * SB;

  __shared__ unsigned short AS[4*8192];  // 4 slots x 256 rows x 32k bf16 (64 KB)
  __shared__ unsigned short BS[4*8192];  // 64 KB

  const int tid  = threadIdx.x;
  const int lane = tid & 63;
  const int w    = tid >> 6;             // 0..7
  const int wr = w >> 2, wc = w & 3;     // 2x4 wave grid, wave out = 128x64

  // ---- A staging: wave w covers rows w*32..+31, 2 gload_lds per slot ----
  const int lrow = lane >> 2, lchunk = lane & 3;
  const unsigned short *ap0, *ap1;
  {
    const int r0 = w*32 + lrow, r1 = w*32 + 16 + lrow;
    const int swz = (lchunk ^ ((r0 >> 1) & 3)) * 8;   // same key for r1 (r1=r0+16)
    int i0 = min(mt*256 + r0, M - 1);
    int i1 = min(mt*256 + r1, M - 1);
    int rowA0 = GATHER ? pair_tok[base + i0] : (GROUPED ? base + i0 : i0);
    int rowA1 = GATHER ? pair_tok[base + i1] : (GROUPED ? base + i1 : i1);
    ap0 = A + (size_t)rowA0 * KV + swz;
    ap1 = A + (size_t)rowA1 * KV + swz;
  }

  // ---- B reg-staging: wave w -> kg = w&3 (k-chunk), nh = w>>2; lane l -> rows {l, l+64} ----
  const int kg = w & 3;
  const int nh = w >> 2;
  const int nnl = nh*128 + lane;                       // first row this lane owns
  const float* bsrc0 = bsrcbase + (size_t)(kg*8) * SB + ncol0 + nnl;
  const int wsl = (kg ^ ((lane >> 1) & 3)) * 16;       // slot key: (nnl>>1)&3 == (lane>>1)&3
  const int wbyteA = nnl*64 + wsl;                     // row nnl
  const int wbyteB = wbyteA + 4096;                    // row nnl+64 (same key)

  const f32x4 zero = {0.f,0.f,0.f,0.f};
  f32x4 acc[8][4];
#pragma unroll
  for (int m = 0; m < 8; ++m)
#pragma unroll
    for (int n = 0; n < 4; ++n) acc[m][n] = zero;

  const int fr = lane & 15;
  const int fg = ((lane >> 4) ^ ((lane >> 1) & 3)) * 16;

  float bregE[16], bregO[16];

#define LOADB(SET, hk)                                                      \
  { const float* _b = bsrc0 + (size_t)(hk) * 32 * SB;                       \
    _Pragma("unroll")                                                       \
    for (int j = 0; j < 8; ++j){                                            \
      SET[j]     = _b[(size_t)j * SB];                                      \
      SET[8 + j] = _b[(size_t)j * SB + 64];                                 \
    } }

#define CVTWRITE(SET, sl)                                                   \
  { uint4 u0, u1;                                                           \
    u0.x = pk2bf(SET[0],  SET[1]);  u0.y = pk2bf(SET[2],  SET[3]);          \
    u0.z = pk2bf(SET[4],  SET[5]);  u0.w = pk2bf(SET[6],  SET[7]);          \
    u1.x = pk2bf(SET[8],  SET[9]);  u1.y = pk2bf(SET[10], SET[11]);         \
    u1.z = pk2bf(SET[12], SET[13]); u1.w = pk2bf(SET[14], SET[15]);         \
    *(uint4*)((char*)BS + (sl)*16384 + wbyteA) = u0;                        \
    *(uint4*)((char*)BS + (sl)*16384 + wbyteB) = u1; }

#define STAGEA(h)                                                           \
  { const int _s = (h) & 3; const size_t _k = (size_t)(h) * 32;             \
    gload_lds16(ap0 + _k, (char*)AS + _s*16384 + (w*32)*64);                \
    gload_lds16(ap1 + _k, (char*)AS + _s*16384 + (w*32+16)*64); }

#define PHASE(h, LSET, WSET)                                                \
  { const int _sl = (h) & 3;                                                \
    const char* _as = (const char*)AS + _sl*16384;                          \
    const char* _bs = (const char*)BS + _sl*16384;                          \
    short8 bq[4], af[8];                                                    \
    _Pragma("unroll")                                                       \
    for (int n = 0; n < 4; ++n)                                             \
      bq[n] = *(const short8*)(_bs + (wc*64 + n*16 + fr)*64 + fg);          \
    _Pragma("unroll")                                                       \
    for (int m = 0; m < 8; ++m)                                             \
      af[m] = *(const short8*)(_as + (wr*128 + m*16 + fr)*64 + fg);         \
    if ((h) + 2 < NH) LOADB(LSET, (h) + 2)                                  \
    if ((h) + 3 < NH) STAGEA((h) + 3)                                       \
    if ((h) + 1 < NH) CVTWRITE(WSET, ((h) + 1) & 3)                         \
    __builtin_amdgcn_s_setprio(1);                                          \
    _Pragma("unroll")                                                       \
    for (int m = 0; m < 8; ++m)                                             \
    _Pragma("unroll")                                                       \
    for (int n = 0; n < 4; ++n)                                             \
      acc[m][n] = __builtin_amdgcn_mfma_f32_16x16x32_bf16(af[m], bq[n], acc[m][n], 0, 0, 0); \
    __builtin_amdgcn_s_setprio(0);                                          \
    if ((h) + 1 < NH){                                                      \
      if ((h) + 3 < NH)      asm volatile("s_waitcnt vmcnt(18) lgkmcnt(0)" ::: "memory"); \
      else if ((h) + 2 < NH) asm volatile("s_waitcnt vmcnt(16) lgkmcnt(0)" ::: "memory"); \
      else                   asm volatile("s_waitcnt vmcnt(0) lgkmcnt(0)" ::: "memory");  \
      __builtin_amdgcn_s_barrier();                                         \
    } }

  // ---- prologue: B slot0 -> E; A slots 0,1,2; write slot0; B slot1 -> O; full drain ----
  LOADB(bregE, 0)
  STAGEA(0) STAGEA(1) STAGEA(2)
  CVTWRITE(bregE, 0)
  LOADB(bregO, 1)
  asm volatile("s_waitcnt vmcnt(0) lgkmcnt(0)" ::: "memory");
  __builtin_amdgcn_s_barrier();

#pragma unroll
  for (int hh = 0; hh < NH; hh += 2){
    PHASE(hh,     bregE, bregO)     // even: load E (h+2), write O (h+1)
    PHASE(hh + 1, bregO, bregE)     // odd:  load O (h+3), write E (h+2)
  }
#undef LOADB
#undef CVTWRITE
#undef STAGEA
#undef PHASE

#pragma unroll
  for (int m = 0; m < 8; ++m)
#pragma unroll
    for (int j = 0; j < 4; ++j){
      const int rr = mt*256 + wr*128 + m*16 + (lane >> 4)*4 + j;
      if (rr < M){
        const int col = n0 + wc*64 + fr;
        if (OUT == 0){
          unsigned short* orow = (unsigned short*)outp + (size_t)(base + rr) * N + col;
#pragma unroll
          for (int n = 0; n < 4; ++n) orow[n*16] = f2bf(acc[m][n][j]);
        } else if (OUT == 1){
          const int p = base + rr;
          const int tok = pair_tok[p];
          const float pw = pair_w[p];
          float* orow = (float*)outp + (size_t)tok * HID + col;
#pragma unroll
          for (int n = 0; n < 4; ++n) atomicAdd(orow + n*16, acc[m][n][j] * pw);
        } else {
          float* orow = (float*)outp + (size_t)rr * N + col;
#pragma unroll
          for (int n = 0; n < 4; ++n) orow[n*16] = acc[m][n][j];
        }
      }
    }
}

extern "C" void kernel_launch(void* const* d_in, const int* in_sizes, int n_in,
                              void* d_out, int out_size, void* d_ws, size_t ws_size,
                              hipStream_t stream)
{
  (void)in_sizes; (void)n_in; (void)out_size; (void)ws_size;
  const float* hid = (const float*)d_in[0];
  const float* rw  = (const float*)d_in[1];
  const float* rb  = (const float*)d_in[2];
  const float* gw  = (const float*)d_in[3];
  const float* uw  = (const float*)d_in[4];
  const float* dw  = (const float*)d_in[5];
  const float* sgw = (const float*)d_in[6];
  const float* suw = (const float*)d_in[7];
  const float* sdw = (const float*)d_in[8];
  float* out = (float*)d_out;

  char* ws = (char*)d_ws;
  size_t o = 0;
  unsigned short* xb   = (unsigned short*)(ws + o); o += (size_t)T_TOK*HID*2;       // 21 MB
  unsigned short* act  = (unsigned short*)(ws + o); o += (size_t)MAXP*FF*2;         // 75.5 MB
  unsigned short* sact = (unsigned short*)(ws + o); o += (size_t)T_TOK*SFF*2;       // 25 MB
  unsigned short* y    = (unsigned short*)(ws + o); o += (size_t)MAXP*2*FF*2;       // 151 MB
  unsigned short* sy   = (unsigned short*)(ws + o); o += (size_t)T_TOK*2*SFF*2;     // 50 MB
  float* top_w    = (float*)(ws + o); o += (size_t)T_TOK*KTOP*4;
  int*   top_i    = (int*)(ws + o);   o += (size_t)T_TOK*KTOP*4;
  float* pair_w   = (float*)(ws + o); o += (size_t)MAXP*4;
  int*   pair_tok = (int*)(ws + o);   o += (size_t)MAXP*4;
  int*   counts   = (int*)(ws + o);   o += NEXP*4;
  int*   offsets  = (int*)(ws + o);   o += (NEXP+1)*4;
  int*   cursor   = (int*)(ws + o);   o += NEXP*4;

  hipMemsetAsync(counts, 0, (NEXP + (NEXP+1) + NEXP) * sizeof(int), stream);

  k_cast_x<<<(T_TOK*HID)/1024, 256, 0, stream>>>(hid, xb);
  k_router<<<T_TOK/4, 256, 0, stream>>>(hid, rw, rb, top_w, top_i, counts);
  k_scan<<<1, 64, 0, stream>>>(counts, offsets);
  k_scatter<<<T_TOK/256, 256, 0, stream>>>(top_i, top_w, offsets, cursor, pair_tok, pair_w);

  // gate+up GEMMs directly from fp32 weights (N' = 2F, gate|up split), then SwiGLU
  k_gemm<true,  true,  0, true,  HID, FF ><<<16*(2*FF/256)*NEXP, 512, 0, stream>>>(
      xb, gw, uw, y, pair_tok, nullptr, counts, offsets, 2*FF, 2*FF/256);
  k_gemm<false, false, 0, true,  HID, SFF><<<16*(2*SFF/256), 512, 0, stream>>>(
      xb, sgw, suw, sy, nullptr, nullptr, nullptr, nullptr, 2*SFF, 2*SFF/256);
  k_swiglu<FF/8><<<(MAXP*(FF/8))/256, 256, 0, stream>>>(y, act);
  k_swiglu<SFF/8><<<(T_TOK*(SFF/8))/256, 256, 0, stream>>>(sy, sact);

  // down GEMMs directly from fp32 weights: shared stores (init), expert atomically accumulates
  k_gemm<false, false, 2, false, SFF, HID><<<16*(HID/256), 512, 0, stream>>>(
      sact, sdw, nullptr, out, nullptr, nullptr, nullptr, nullptr, HID, HID/256);
  k_gemm<true,  false, 1, false, FF,  HID><<<16*(HID/256)*NEXP, 512, 0, stream>>>(
      act, dw, nullptr, out, pair_tok, pair_w, counts, offsets, HID, HID/256);
}